// Round 8
// baseline (203.032 us; speedup 1.0000x reference)
//
#include <hip/hip_runtime.h>
#include <hip/hip_bf16.h>
#include <cstdint>
#include <cstddef>

#define L_SEQ 4096
#define BATCH_N 4
#define HID 1024
#define DH 256
// log2(0.96875)
#define LOG2_GAMMA (-0.045803689613124953f)
// 0.96875^-32
#define INV_GAMMA32 (2.7620582f)

typedef __attribute__((ext_vector_type(8))) short short8;
typedef __attribute__((ext_vector_type(4))) float floatx4;

__device__ __forceinline__ unsigned short f2bf(float f) {
    union { float f; unsigned int u; } v; v.f = f;
    unsigned int r = (v.u + 0x7FFFu + ((v.u >> 16) & 1u)) >> 16;  // RNE
    return (unsigned short)r;
}

__device__ __forceinline__ void async_copy16(const unsigned short* gsrc,
                                             unsigned short* lds) {
    __builtin_amdgcn_global_load_lds(
        (const __attribute__((address_space(1))) unsigned int*)gsrc,
        (__attribute__((address_space(3))) unsigned int*)lds, 16, 0, 0);
}

// ---------------------------------------------------------------------------
// Kernel P: fused preprocessing. Block-range sections:
//   [0,16384)        : X fp32 -> bf16                  (convert_x)
//   [16384,18432)    : xpos coefficient tables          (xpos_table)
//   [18432,18624)    : W transpose+convert -> Wt        (transpose_w)
// ROUND 8: O-zero section removed (retention no longer uses atomics).
// ---------------------------------------------------------------------------
__global__ __launch_bounds__(256) void prep_kernel(
    const float* __restrict__ X, unsigned short* __restrict__ Xb,
    float2* __restrict__ tabQ, float2* __restrict__ tabK,
    const float* __restrict__ WQ, const float* __restrict__ WK,
    const float* __restrict__ WV, unsigned short* __restrict__ Wt)
{
    __shared__ float Ts[64][68];   // used by the transpose section only
    const int bid = blockIdx.x;
    const int t   = threadIdx.x;

    if (bid < 16384) {
        // ---- convert X ----
        const int i = (bid * 256 + t) * 4;
        const float4 v = *(const float4*)&X[i];
        ushort4 p;
        p.x = f2bf(v.x); p.y = f2bf(v.y); p.z = f2bf(v.z); p.w = f2bf(v.w);
        *(ushort4*)&Xb[i] = p;
    } else if (bid < 18432) {
        // ---- xpos tables: tab[i2][pos], pos-major ----
        const int gid = (bid - 16384) * 256 + t;          // 0 .. 524287
        const int i2  = gid >> 12;                        // 0..127
        const int pos = gid & (L_SEQ - 1);
        const float e   = (float)pos * (1.0f / 512.0f);
        const float sb  = ((float)(2 * i2) + 102.4f) * (1.0f / 358.4f);
        const float scQ = exp2f(log2f(sb) * e);
        const float scK = 1.0f / scQ;
        const float invf = exp2f(-13.287712379549449f *
                                 ((float)i2 * (1.0f / 128.0f)));
        float s, c;
        sincosf((float)pos * invf, &s, &c);
        tabQ[gid] = make_float2(c * scQ, s * scQ);
        tabK[gid] = make_float2(c * scK, s * scK);
    } else {
        // ---- W transpose: [1024][256] fp32 -> Wt bf16 [768][1024] ----
        const int idx = bid - 18432;          // 0..191
        const int n0 = (idx % 12) * 64;       // 0..704
        const int k0 = (idx / 12) * 64;       // 0..960
        const int seg = n0 >> 8;
        const float* __restrict__ W = (seg == 0) ? WQ : (seg == 1) ? WK : WV;
        const int nl0 = n0 & 255;

        const int r  = t >> 4;          // 0..15
        const int c4 = (t & 15) * 4;
        #pragma unroll
        for (int i = 0; i < 4; ++i) {
            const int kk = r + i * 16;
            const float4 v = *(const float4*)&W[(size_t)(k0 + kk) * DH + nl0 + c4];
            Ts[c4 + 0][kk] = v.x;
            Ts[c4 + 1][kk] = v.y;
            Ts[c4 + 2][kk] = v.z;
            Ts[c4 + 3][kk] = v.w;
        }
        __syncthreads();
        const int rn = t >> 3;          // 0..31
        const int c8 = (t & 7) * 8;
        #pragma unroll
        for (int i = 0; i < 2; ++i) {
            const int rr = rn + i * 32;
            ushort4 p0, p1;
            p0.x = f2bf(Ts[rr][c8 + 0]); p0.y = f2bf(Ts[rr][c8 + 1]);
            p0.z = f2bf(Ts[rr][c8 + 2]); p0.w = f2bf(Ts[rr][c8 + 3]);
            p1.x = f2bf(Ts[rr][c8 + 4]); p1.y = f2bf(Ts[rr][c8 + 5]);
            p1.z = f2bf(Ts[rr][c8 + 6]); p1.w = f2bf(Ts[rr][c8 + 7]);
            unsigned short* dst = &Wt[(size_t)(n0 + rr) * HID + k0 + c8];
            *(ushort4*)dst       = p0;
            *(ushort4*)(dst + 4) = p1;
        }
    }
}

// ---------------------------------------------------------------------------
// Kernel C: QKV projection via bf16 MFMA, output-transposed D[n][pos].
//   ROUND 8: BK=64, 2-buffer, phase-split schedule (T3/T4):
//     vmcnt(8) [counted: next tile's 8 loads stay in flight] -> barrier ->
//     16x ds_read_b128 (all frags) -> lgkmcnt(0) -> barrier ->
//     stage(kt+2) [8x global_load_lds, race-free: all reads drained] ->
//     32 back-to-back MFMAs overlapping the in-flight loads.
//   Chunk-XOR layout p = s ^ (row&7): write side 8 lanes = one contiguous
//   128B row segment (coalesced); read side 2-way bank aliasing (free).
//   LDS 64 KB -> 2 blocks/CU.
// ---------------------------------------------------------------------------
__global__ __launch_bounds__(256) void gemm_qkv_kernel(
    const unsigned short* __restrict__ Wt,   // [768][1024]
    const unsigned short* __restrict__ Xb,   // [16384][1024]
    const float2* __restrict__ tabQ,         // [128][4096]
    const float2* __restrict__ tabK,         // [128][4096]
    unsigned short* __restrict__ Qo,
    unsigned short* __restrict__ Ko,
    unsigned short* __restrict__ VtG)
{
    __shared__ unsigned short Wa[2][128][64];   // 32 KB  [buf][row][chunked]
    __shared__ unsigned short Xs[2][128][64];   // 32 KB

    // XCD swizzle: 768 = 8 xcd * 96; per-XCD 96 blocks = 16 p-tiles x 6 n-tiles
    const int dblk = blockIdx.x;
    const int xcd  = dblk & 7;
    const int sq   = dblk >> 3;        // 0..95
    const int by   = xcd * 16 + sq / 6;
    const int bx   = sq % 6;

    const int n0 = bx * 128;   // 0..640
    const int p0 = by * 128;   // 0..16256
    const int t    = threadIdx.x;
    const int w    = t >> 6;
    const int lane = t & 63;
    const int quad = lane >> 4;
    const int l16  = lane & 15;
    const int wn   = (w & 1) * 64;
    const int wp   = (w >> 1) * 64;

    floatx4 acc[4][4];
    #pragma unroll
    for (int i = 0; i < 4; ++i)
        #pragma unroll
        for (int j = 0; j < 4; ++j) acc[i][j] = (floatx4){0.f, 0.f, 0.f, 0.f};

    const int NT = HID / 64;   // 16 K-tiles

    // stage one 128x64 tile pair: 8 async ops/thread. Wave w covers rows
    // w*8 + is*32 + (lane>>3); physical chunk p = lane&7 holds semantic
    // chunk s = p ^ (row&7)  (row&7 == lane>>3).
    const int g8 = lane >> 3;          // 0..7
    const int pc = lane & 7;           // physical chunk
    const int sc = (pc ^ g8) * 8;      // semantic source col (shorts)
    auto stage = [&](int buf, int kt) {
        const int k0 = kt * 64;
        #pragma unroll
        for (int is = 0; is < 4; ++is) {
            const int gr = w * 8 + is * 32 + g8;   // row in 128-tile
            const unsigned short* ga =
                &Wt[(size_t)(n0 + gr) * HID + k0 + sc];
            const unsigned short* gb =
                &Xb[(size_t)(p0 + gr) * HID + k0 + sc];
            async_copy16(ga, &Wa[buf][is * 32 + w * 8][0]);
            async_copy16(gb, &Xs[buf][is * 32 + w * 8][0]);
        }
    };

    // prologue: 2 tiles in flight (16 outstanding vmem ops per thread)
    stage(0, 0);
    stage(1, 1);

    const int xr = l16 & 7;   // read-side XOR key

    for (int kt = 0; kt < NT; ++kt) {
        const int buf = kt & 1;
        // tile kt's 8 loads are the oldest: counted wait keeps tile kt+1's
        // 8 in flight across the barrier (never vmcnt(0) mid-loop)
        if (kt + 1 < NT)
            asm volatile("s_waitcnt vmcnt(8)" ::: "memory");
        else
            asm volatile("s_waitcnt vmcnt(0)" ::: "memory");
        __builtin_amdgcn_s_barrier();

        // read ALL fragments for this 64-wide K-tile into registers
        const char* wbp = (const char*)&Wa[buf][0][0];
        const char* xbp = (const char*)&Xs[buf][0][0];
        short8 af[2][4], bfv[2][4];
        #pragma unroll
        for (int kk = 0; kk < 2; ++kk) {
            const int pk = (((kk << 2) | quad) ^ xr) << 4;   // chunk byte
            #pragma unroll
            for (int nt = 0; nt < 4; ++nt) {
                af[kk][nt]  = *(const short8*)(wbp + (wn + nt * 16 + l16) * 128 + pk);
                bfv[kk][nt] = *(const short8*)(xbp + (wp + nt * 16 + l16) * 128 + pk);
            }
        }
        // my reads done; barrier => ALL waves' reads done -> buf reusable
        asm volatile("s_waitcnt lgkmcnt(0)" ::: "memory");
        __builtin_amdgcn_s_barrier();

        // refill this buffer for tile kt+2 while MFMAs run
        if (kt + 2 < NT) stage(buf, kt + 2);

        #pragma unroll
        for (int kk = 0; kk < 2; ++kk)
            #pragma unroll
            for (int nt = 0; nt < 4; ++nt)
                #pragma unroll
                for (int pt = 0; pt < 4; ++pt)
                    acc[nt][pt] = __builtin_amdgcn_mfma_f32_16x16x32_bf16(
                        af[kk][nt], bfv[kk][pt], acc[nt][pt], 0, 0, 0);
    }

    // ---- epilogue ----
    const int seg = n0 >> 8;     // 0=Q 1=K 2=V
    const float2* __restrict__ tab = (seg == 1) ? tabK : tabQ;
    #pragma unroll
    for (int nt = 0; nt < 4; ++nt) {
        const int nfeat = n0 + wn + nt * 16 + quad * 4;  // feat of reg g=0
        const int d0 = nfeat & 255;                      // segment-local
        #pragma unroll
        for (int pt = 0; pt < 4; ++pt) {
            const int pg  = p0 + wp + pt * 16 + l16;     // global row
            const int b   = pg >> 12;
            const int pos = pg & (L_SEQ - 1);
            if (seg == 2) {
                #pragma unroll
                for (int g = 0; g < 4; ++g)
                    VtG[(((size_t)(b * 256 + d0 + g)) << 12) + pos] =
                        f2bf(acc[nt][pt][g]);
            } else {
                float res[4];
                #pragma unroll
                for (int h = 0; h < 4; h += 2) {
                    const int i2 = (d0 + h) >> 1;
                    const float2 tc = tab[(i2 << 12) + pos];
                    const float cs = tc.x, ss = tc.y;
                    const float xe = acc[nt][pt][h], xo = acc[nt][pt][h + 1];
                    res[h]     = xe * cs - xo * ss;
                    res[h + 1] = xo * cs + xe * ss;
                }
                ushort4 pk;
                pk.x = f2bf(res[0]); pk.y = f2bf(res[1]);
                pk.z = f2bf(res[2]); pk.w = f2bf(res[3]);
                unsigned short* orow =
                    ((seg == 0) ? Qo : Ko) + (size_t)pg * DH + d0;
                *(ushort4*)orow = pk;
            }
        }
    }
}

// ---------------------------------------------------------------------------
// Kernel D: windowed retention via bf16 MFMA.
//   ROUND 8: z-split by FEATURE-half (not window-half). Each block computes
//   the full decay window but only 128 of 256 V-features: QK^T duplicated
//   (+33% MFMA) but epilogue is a direct store — the 8.4M global fp32
//   atomicAdds and the 16MB O-zero pass are eliminated. V staging halves.
//   LDS 26.5 KB. Swapped QK^T + in-register P redistribution kept from R4.
// ---------------------------------------------------------------------------
__global__ __launch_bounds__(256) void retention_kernel(
    const unsigned short* __restrict__ Q,
    const unsigned short* __restrict__ K,
    const unsigned short* __restrict__ VtG,
    float* __restrict__ O)
{
    __shared__ short Ks[32][264];    // 16.5 KB
    __shared__ short Vt[128][40];    // 10 KB

    const int dblk = blockIdx.x;
    const int xcd  = dblk & 7;
    const int sq   = dblk >> 3;           // 0..63
    const int qt   = xcd * 8 + (sq & 7);  // 0..63
    const int b    = (sq >> 3) & 3;
    const int z    = sq >> 5;             // feature half: d in [z*128, z*128+128)

    const int t  = threadIdx.x;
    const int q0 = qt * 64;

    const int w    = t >> 6;
    const int lane = t & 63;
    const int quad = lane >> 4;
    const int l16  = lane & 15;
    const int w16  = w * 16;

    const size_t rbase = (size_t)b * L_SEQ * DH;
    const size_t vbase = ((size_t)b * DH) << 12;

    // full window [kst, q0+64); length is always a multiple of 32
    int kst = q0 - 512; if (kst < 0) kst = 0;
    const int kfin = q0 + 64;

    // Q fragments in registers: B-frag for swapped mfma.
    short8 qf[8];
    {
        const unsigned short* qsrc = Q + rbase + (size_t)(q0 + w16 + l16) * DH;
        #pragma unroll
        for (int dd = 0; dd < 8; ++dd)
            qf[dd] = *(const short8*)&qsrc[dd * 32 + quad * 8];
    }

    // running decay state per (nt,g): d = qpos - kpos at current k0
    int   dint[8];
    float dec[8];
    #pragma unroll
    for (int nt = 0; nt < 2; ++nt)
        #pragma unroll
        for (int g = 0; g < 4; ++g) {
            const int idx = nt * 4 + g;
            dint[idx] = (q0 + w16 + l16) - (kst + nt * 16 + quad * 4 + g);
            dec[idx]  = exp2f((float)dint[idx] * LOG2_GAMMA);
        }

    floatx4 o[8];
    #pragma unroll
    for (int f = 0; f < 8; ++f) o[f] = (floatx4){0.f, 0.f, 0.f, 0.f};

    // bpermute source-lane byte indices (constant per lane)
    const int s0   = (quad & 1) * 2;
    const int idxA = (s0 * 16 + l16) * 4;
    const int idxB = idxA + 64;
    const bool lo  = (quad < 2);   // target k-subtile nt = quad>>1

    for (int k0 = kst; k0 < kfin; k0 += 32) {
        __syncthreads();   // all reads of Ks/Vt from previous step done
        {
            const unsigned short* src = K + rbase + (size_t)k0 * DH;
            #pragma unroll
            for (int i = 0; i < 4; ++i) {
                const int row = i * 8 + (t >> 5);
                const int col = (t & 31) * 8;
                *(uint4*)&Ks[row][col] = *(const uint4*)&src[row * DH + col];
            }
        }
        {
            const int c0   = t >> 2;           // 0..63
            const int koff = (t & 3) * 8;
            #pragma unroll
            for (int i = 0; i < 2; ++i) {
                const int c = c0 + 64 * i;     // feature-local row 0..127
                *(uint4*)&Vt[c][koff] =
                    *(const uint4*)&VtG[vbase + ((size_t)(z * 128 + c) << 12) +
                                        k0 + koff];
            }
        }
        __syncthreads();   // staging visible

        // ---- swapped QK^T: A = K rows, B = Q regs; 4 independent chains
        floatx4 sA0 = (floatx4){0.f, 0.f, 0.f, 0.f};
        floatx4 sA1 = (floatx4){0.f, 0.f, 0.f, 0.f};
        floatx4 sB0 = (floatx4){0.f, 0.f, 0.f, 0.f};
        floatx4 sB1 = (floatx4){0.f, 0.f, 0.f, 0.f};
        #pragma unroll
        for (int dd = 0; dd < 4; ++dd) {
            const short8 k0f = *(const short8*)&Ks[l16][dd * 32 + quad * 8];
            const short8 k1f = *(const short8*)&Ks[16 + l16][dd * 32 + quad * 8];
            const short8 k0g = *(const short8*)&Ks[l16][(dd + 4) * 32 + quad * 8];
            const short8 k1g = *(const short8*)&Ks[16 + l16][(dd + 4) * 32 + quad * 8];
            sA0 = __builtin_amdgcn_mfma_f32_16x16x32_bf16(k0f, qf[dd], sA0, 0, 0, 0);
            sA1 = __builtin_amdgcn_mfma_f32_16x16x32_bf16(k1f, qf[dd], sA1, 0, 0, 0);
            sB0 = __builtin_amdgcn_mfma_f32_16x16x32_bf16(k0g, qf[dd + 4], sB0, 0, 0, 0);
            sB1 = __builtin_amdgcn_mfma_f32_16x16x32_bf16(k1g, qf[dd + 4], sB1, 0, 0, 0);
        }
        const floatx4 sv0 = sA0 + sB0;   // nt=0: kpos = k0 + quad*4+g
        const floatx4 sv1 = sA1 + sB1;   // nt=1: kpos = k0+16 + quad*4+g

        // ---- decay + pack to bf16 pairs (lane-local)
        unsigned int pk01[2], pk23[2];
        #pragma unroll
        for (int nt = 0; nt < 2; ++nt) {
            const floatx4 sv = nt ? sv1 : sv0;
            float pv[4];
            #pragma unroll
            for (int g = 0; g < 4; ++g) {
                const int idx = nt * 4 + g;
                pv[g] = (dint[idx] >= 0) ? sv[g] * dec[idx] : 0.0f;
            }
            pk01[nt] = ((unsigned int)f2bf(pv[1]) << 16) | (unsigned int)f2bf(pv[0]);
            pk23[nt] = ((unsigned int)f2bf(pv[3]) << 16) | (unsigned int)f2bf(pv[2]);
        }
        #pragma unroll
        for (int i = 0; i < 8; ++i) { dint[i] -= 32; dec[i] *= INV_GAMMA32; }

        // ---- redistribute P to PV A-frag layout: 8 bpermute + 4 selects
        const int a01_0 = __builtin_amdgcn_ds_bpermute(idxA, (int)pk01[0]);
        const int a01_1 = __builtin_amdgcn_ds_bpermute(idxA, (int)pk01[1]);
        const int a23_0 = __builtin_amdgcn_ds_bpermute(idxA, (int)pk23[0]);
        const int a23_1 = __builtin_amdgcn_ds_bpermute(idxA, (int)pk23[1]);
        const int b01_0 = __builtin_amdgcn_ds_bpermute(idxB, (int)pk01[0]);
        const int b01_1 = __builtin_amdgcn_ds_bpermute(idxB, (int)pk01[1]);
        const int b23_0 = __builtin_amdgcn_ds_bpermute(idxB, (int)pk23[0]);
        const int b23_1 = __builtin_amdgcn_ds_bpermute(idxB, (int)pk23[1]);
        union { int u[4]; short8 s8; } af;
        af.u[0] = lo ? a01_0 : a01_1;
        af.u[1] = lo ? a23_0 : a23_1;
        af.u[2] = lo ? b01_0 : b01_1;
        af.u[3] = lo ? b23_0 : b23_1;

        // ---- PV: o[f] += P @ V^T  (A from regs, B from Vt LDS; 8 features)
        #pragma unroll
        for (int f = 0; f < 8; ++f) {
            const short8 bfr = *(const short8*)&Vt[f * 16 + l16][quad * 8];
            o[f] = __builtin_amdgcn_mfma_f32_16x16x32_bf16(af.s8, bfr, o[f], 0, 0, 0);
        }
    }

    // direct store: this block owns features z*128 .. z*128+127 exclusively
    #pragma unroll
    for (int f = 0; f < 8; ++f) {
        #pragma unroll
        for (int g = 0; g < 4; ++g) {
            const int qpos = q0 + w16 + quad * 4 + g;
            O[rbase + (size_t)qpos * DH + z * 128 + f * 16 + l16] = o[f][g];
        }
    }
}

// ---------------------------------------------------------------------------
extern "C" void kernel_launch(void* const* d_in, const int* in_sizes, int n_in,
                              void* d_out, int out_size, void* d_ws, size_t ws_size,
                              hipStream_t stream)
{
    const float* X  = (const float*)d_in[0];
    const float* WQ = (const float*)d_in[1];
    const float* WK = (const float*)d_in[2];
    const float* WV = (const float*)d_in[3];
    float* out = (float*)d_out;

    const size_t per = (size_t)BATCH_N * L_SEQ * DH;   // 4,194,304
    unsigned short* Qw  = (unsigned short*)d_ws;
    unsigned short* Kw  = Qw + per;
    unsigned short* Vtw = Kw + per;
    unsigned short* Xbw = Vtw + per;                   // 16,777,216 elems
    unsigned short* Wtw = Xbw + (size_t)16384 * HID;   // 786,432 elems
    float2* tabQ = (float2*)(Wtw + 786432);            // 4 MB (8B-aligned)
    float2* tabK = tabQ + (size_t)128 * L_SEQ;         // 4 MB
    // total workspace: ~68.3 MB

    // fused prep: convert X, build tables, transpose W (no O-zero needed)
    prep_kernel<<<18624, 256, 0, stream>>>(X, Xbw, tabQ, tabK,
                                           WQ, WK, WV, Wtw);

    gemm_qkv_kernel<<<768, 256, 0, stream>>>(Wtw, Xbw, tabQ, tabK, Qw, Kw, Vtw);

    retention_kernel<<<512, 256, 0, stream>>>(Qw, Kw, Vtw, out);
}

// Round 9
// 187.654 us; speedup vs baseline: 1.0819x; 1.0819x over previous
//
#include <hip/hip_runtime.h>
#include <hip/hip_bf16.h>
#include <cstdint>
#include <cstddef>

#define L_SEQ 4096
#define BATCH_N 4
#define HID 1024
#define DH 256
// log2(0.96875)
#define LOG2_GAMMA (-0.045803689613124953f)
// 0.96875^-32
#define INV_GAMMA32 (2.7620582f)

typedef __attribute__((ext_vector_type(8))) short short8;
typedef __attribute__((ext_vector_type(4))) float floatx4;

__device__ __forceinline__ unsigned short f2bf(float f) {
    union { float f; unsigned int u; } v; v.f = f;
    unsigned int r = (v.u + 0x7FFFu + ((v.u >> 16) & 1u)) >> 16;  // RNE
    return (unsigned short)r;
}

__device__ __forceinline__ void async_copy16(const unsigned short* gsrc,
                                             unsigned short* lds) {
    __builtin_amdgcn_global_load_lds(
        (const __attribute__((address_space(1))) unsigned int*)gsrc,
        (__attribute__((address_space(3))) unsigned int*)lds, 16, 0, 0);
}

// ---------------------------------------------------------------------------
// Kernel P: fused preprocessing (unchanged from round 8).
//   [0,16384)        : X fp32 -> bf16
//   [16384,18432)    : xpos coefficient tables
//   [18432,18624)    : W transpose+convert -> Wt
// ---------------------------------------------------------------------------
__global__ __launch_bounds__(256) void prep_kernel(
    const float* __restrict__ X, unsigned short* __restrict__ Xb,
    float2* __restrict__ tabQ, float2* __restrict__ tabK,
    const float* __restrict__ WQ, const float* __restrict__ WK,
    const float* __restrict__ WV, unsigned short* __restrict__ Wt)
{
    __shared__ float Ts[64][68];   // used by the transpose section only
    const int bid = blockIdx.x;
    const int t   = threadIdx.x;

    if (bid < 16384) {
        const int i = (bid * 256 + t) * 4;
        const float4 v = *(const float4*)&X[i];
        ushort4 p;
        p.x = f2bf(v.x); p.y = f2bf(v.y); p.z = f2bf(v.z); p.w = f2bf(v.w);
        *(ushort4*)&Xb[i] = p;
    } else if (bid < 18432) {
        const int gid = (bid - 16384) * 256 + t;          // 0 .. 524287
        const int i2  = gid >> 12;                        // 0..127
        const int pos = gid & (L_SEQ - 1);
        const float e   = (float)pos * (1.0f / 512.0f);
        const float sb  = ((float)(2 * i2) + 102.4f) * (1.0f / 358.4f);
        const float scQ = exp2f(log2f(sb) * e);
        const float scK = 1.0f / scQ;
        const float invf = exp2f(-13.287712379549449f *
                                 ((float)i2 * (1.0f / 128.0f)));
        float s, c;
        sincosf((float)pos * invf, &s, &c);
        tabQ[gid] = make_float2(c * scQ, s * scQ);
        tabK[gid] = make_float2(c * scK, s * scK);
    } else {
        const int idx = bid - 18432;          // 0..191
        const int n0 = (idx % 12) * 64;       // 0..704
        const int k0 = (idx / 12) * 64;       // 0..960
        const int seg = n0 >> 8;
        const float* __restrict__ W = (seg == 0) ? WQ : (seg == 1) ? WK : WV;
        const int nl0 = n0 & 255;

        const int r  = t >> 4;          // 0..15
        const int c4 = (t & 15) * 4;
        #pragma unroll
        for (int i = 0; i < 4; ++i) {
            const int kk = r + i * 16;
            const float4 v = *(const float4*)&W[(size_t)(k0 + kk) * DH + nl0 + c4];
            Ts[c4 + 0][kk] = v.x;
            Ts[c4 + 1][kk] = v.y;
            Ts[c4 + 2][kk] = v.z;
            Ts[c4 + 3][kk] = v.w;
        }
        __syncthreads();
        const int rn = t >> 3;          // 0..31
        const int c8 = (t & 7) * 8;
        #pragma unroll
        for (int i = 0; i < 2; ++i) {
            const int rr = rn + i * 32;
            ushort4 p0, p1;
            p0.x = f2bf(Ts[rr][c8 + 0]); p0.y = f2bf(Ts[rr][c8 + 1]);
            p0.z = f2bf(Ts[rr][c8 + 2]); p0.w = f2bf(Ts[rr][c8 + 3]);
            p1.x = f2bf(Ts[rr][c8 + 4]); p1.y = f2bf(Ts[rr][c8 + 5]);
            p1.z = f2bf(Ts[rr][c8 + 6]); p1.w = f2bf(Ts[rr][c8 + 7]);
            unsigned short* dst = &Wt[(size_t)(n0 + rr) * HID + k0 + c8];
            *(ushort4*)dst       = p0;
            *(ushort4*)(dst + 4) = p1;
        }
    }
}

// ---------------------------------------------------------------------------
// Kernel C: QKV projection via bf16 MFMA (unchanged from round 8).
//   BK=64, 2-buffer, counted-vmcnt phase-split, chunk-XOR LDS layout.
// ---------------------------------------------------------------------------
__global__ __launch_bounds__(256) void gemm_qkv_kernel(
    const unsigned short* __restrict__ Wt,   // [768][1024]
    const unsigned short* __restrict__ Xb,   // [16384][1024]
    const float2* __restrict__ tabQ,         // [128][4096]
    const float2* __restrict__ tabK,         // [128][4096]
    unsigned short* __restrict__ Qo,
    unsigned short* __restrict__ Ko,
    unsigned short* __restrict__ VtG)
{
    __shared__ unsigned short Wa[2][128][64];   // 32 KB
    __shared__ unsigned short Xs[2][128][64];   // 32 KB

    const int dblk = blockIdx.x;
    const int xcd  = dblk & 7;
    const int sq   = dblk >> 3;        // 0..95
    const int by   = xcd * 16 + sq / 6;
    const int bx   = sq % 6;

    const int n0 = bx * 128;   // 0..640
    const int p0 = by * 128;   // 0..16256
    const int t    = threadIdx.x;
    const int w    = t >> 6;
    const int lane = t & 63;
    const int quad = lane >> 4;
    const int l16  = lane & 15;
    const int wn   = (w & 1) * 64;
    const int wp   = (w >> 1) * 64;

    floatx4 acc[4][4];
    #pragma unroll
    for (int i = 0; i < 4; ++i)
        #pragma unroll
        for (int j = 0; j < 4; ++j) acc[i][j] = (floatx4){0.f, 0.f, 0.f, 0.f};

    const int NT = HID / 64;   // 16 K-tiles

    const int g8 = lane >> 3;          // 0..7
    const int pc = lane & 7;           // physical chunk
    const int sc = (pc ^ g8) * 8;      // semantic source col (shorts)
    auto stage = [&](int buf, int kt) {
        const int k0 = kt * 64;
        #pragma unroll
        for (int is = 0; is < 4; ++is) {
            const int gr = w * 8 + is * 32 + g8;   // row in 128-tile
            const unsigned short* ga =
                &Wt[(size_t)(n0 + gr) * HID + k0 + sc];
            const unsigned short* gb =
                &Xb[(size_t)(p0 + gr) * HID + k0 + sc];
            async_copy16(ga, &Wa[buf][is * 32 + w * 8][0]);
            async_copy16(gb, &Xs[buf][is * 32 + w * 8][0]);
        }
    };

    stage(0, 0);
    stage(1, 1);

    const int xr = l16 & 7;   // read-side XOR key

    for (int kt = 0; kt < NT; ++kt) {
        const int buf = kt & 1;
        if (kt + 1 < NT)
            asm volatile("s_waitcnt vmcnt(8)" ::: "memory");
        else
            asm volatile("s_waitcnt vmcnt(0)" ::: "memory");
        __builtin_amdgcn_s_barrier();

        const char* wbp = (const char*)&Wa[buf][0][0];
        const char* xbp = (const char*)&Xs[buf][0][0];
        short8 af[2][4], bfv[2][4];
        #pragma unroll
        for (int kk = 0; kk < 2; ++kk) {
            const int pk = (((kk << 2) | quad) ^ xr) << 4;   // chunk byte
            #pragma unroll
            for (int nt = 0; nt < 4; ++nt) {
                af[kk][nt]  = *(const short8*)(wbp + (wn + nt * 16 + l16) * 128 + pk);
                bfv[kk][nt] = *(const short8*)(xbp + (wp + nt * 16 + l16) * 128 + pk);
            }
        }
        asm volatile("s_waitcnt lgkmcnt(0)" ::: "memory");
        __builtin_amdgcn_s_barrier();

        if (kt + 2 < NT) stage(buf, kt + 2);

        #pragma unroll
        for (int kk = 0; kk < 2; ++kk)
            #pragma unroll
            for (int nt = 0; nt < 4; ++nt)
                #pragma unroll
                for (int pt = 0; pt < 4; ++pt)
                    acc[nt][pt] = __builtin_amdgcn_mfma_f32_16x16x32_bf16(
                        af[kk][nt], bfv[kk][pt], acc[nt][pt], 0, 0, 0);
    }

    // ---- epilogue ----
    const int seg = n0 >> 8;     // 0=Q 1=K 2=V
    const float2* __restrict__ tab = (seg == 1) ? tabK : tabQ;
    #pragma unroll
    for (int nt = 0; nt < 4; ++nt) {
        const int nfeat = n0 + wn + nt * 16 + quad * 4;  // feat of reg g=0
        const int d0 = nfeat & 255;                      // segment-local
        #pragma unroll
        for (int pt = 0; pt < 4; ++pt) {
            const int pg  = p0 + wp + pt * 16 + l16;     // global row
            const int b   = pg >> 12;
            const int pos = pg & (L_SEQ - 1);
            if (seg == 2) {
                #pragma unroll
                for (int g = 0; g < 4; ++g)
                    VtG[(((size_t)(b * 256 + d0 + g)) << 12) + pos] =
                        f2bf(acc[nt][pt][g]);
            } else {
                float res[4];
                #pragma unroll
                for (int h = 0; h < 4; h += 2) {
                    const int i2 = (d0 + h) >> 1;
                    const float2 tc = tab[(i2 << 12) + pos];
                    const float cs = tc.x, ss = tc.y;
                    const float xe = acc[nt][pt][h], xo = acc[nt][pt][h + 1];
                    res[h]     = xe * cs - xo * ss;
                    res[h + 1] = xo * cs + xe * ss;
                }
                ushort4 pk;
                pk.x = f2bf(res[0]); pk.y = f2bf(res[1]);
                pk.z = f2bf(res[2]); pk.w = f2bf(res[3]);
                unsigned short* orow =
                    ((seg == 0) ? Qo : Ko) + (size_t)pg * DH + d0;
                *(ushort4*)orow = pk;
            }
        }
    }
}

// ---------------------------------------------------------------------------
// Kernel D: windowed retention via bf16 MFMA.
//   ROUND 9: T3 minimum-2-phase pipeline. Double-buffered UNPADDED K/V LDS
//   staged via global_load_lds with XOR-pre-swizzled sources (rule #21:
//   source permutation == read permutation):
//     K [2][32][256]: s = p ^ (row&7);  QK read p = (dd*4+quad)^(l16&7)
//       -> write 32 lanes = one 512B row (coalesced), read 2-way (free).
//     V [2][128][32]: s = p ^ ((row>>1)&3); PV read p = quad^((l16>>1)&3)
//       -> write 4 lanes = one 64B row, read 2-way (fixes R8's 4.4M
//       8-way conflict).
//   One s_barrier per step: stage(next) -> compute(cur) -> vmcnt(0) ->
//   barrier. Loads overlap the whole compute phase. setprio around MFMAs.
//   Feature-half z-split + direct stores kept from R8.
// ---------------------------------------------------------------------------
__global__ __launch_bounds__(256) void retention_kernel(
    const unsigned short* __restrict__ Q,
    const unsigned short* __restrict__ K,
    const unsigned short* __restrict__ VtG,
    float* __restrict__ O)
{
    __shared__ unsigned short Ks[2][32][256];   // 32 KB
    __shared__ unsigned short Vt[2][128][32];   // 16 KB

    const int dblk = blockIdx.x;
    const int xcd  = dblk & 7;
    const int sq   = dblk >> 3;           // 0..63
    const int qt   = xcd * 8 + (sq & 7);  // 0..63
    const int b    = (sq >> 3) & 3;
    const int z    = sq >> 5;             // feature half

    const int t  = threadIdx.x;
    const int q0 = qt * 64;

    const int w    = t >> 6;
    const int lane = t & 63;
    const int quad = lane >> 4;
    const int l16  = lane & 15;
    const int w16  = w * 16;

    const size_t rbase = (size_t)b * L_SEQ * DH;
    const size_t vbase = ((size_t)b * DH) << 12;

    int kst = q0 - 512; if (kst < 0) kst = 0;
    const int nsteps = ((q0 + 64) - kst) >> 5;

    // ---- staging constants (source pre-swizzle) ----
    // K: issue i covers LDS rows i*8 + w*2 + (lane>>5), chunk p = lane&31;
    //    semantic col = (p ^ (row&7))*8 shorts; row&7 independent of i.
    const int krow = w * 2 + (lane >> 5);               // + i*8
    const int kscol = ((lane & 31) ^ (krow & 7)) * 8;
    // V: issue i covers LDS rows i*64 + w*16 + (lane>>2), chunk p = lane&3;
    //    semantic col = (p ^ ((row>>1)&3))*8 = (p ^ ((lane>>3)&3))*8.
    const int vrow = w * 16 + (lane >> 2);              // + i*64
    const int vscol = ((lane & 3) ^ ((lane >> 3) & 3)) * 8;

    auto stage = [&](int buf, int k0) {
        const unsigned short* ksrc = K + rbase + (size_t)k0 * DH;
        #pragma unroll
        for (int i = 0; i < 4; ++i)
            async_copy16(&ksrc[(size_t)(i * 8 + krow) * DH + kscol],
                         &Ks[buf][i * 8 + w * 2][0]);
        #pragma unroll
        for (int i = 0; i < 2; ++i)
            async_copy16(&VtG[vbase + ((size_t)(z * 128 + i * 64 + vrow) << 12) +
                              k0 + vscol],
                         &Vt[buf][i * 64 + w * 16][0]);
    };

    // Q fragments in registers: B-frag for swapped mfma.
    short8 qf[8];
    {
        const unsigned short* qsrc = Q + rbase + (size_t)(q0 + w16 + l16) * DH;
        #pragma unroll
        for (int dd = 0; dd < 8; ++dd)
            qf[dd] = *(const short8*)&qsrc[dd * 32 + quad * 8];
    }

    // running decay state per (nt,g): d = qpos - kpos at current k0
    int   dint[8];
    float dec[8];
    #pragma unroll
    for (int nt = 0; nt < 2; ++nt)
        #pragma unroll
        for (int g = 0; g < 4; ++g) {
            const int idx = nt * 4 + g;
            dint[idx] = (q0 + w16 + l16) - (kst + nt * 16 + quad * 4 + g);
            dec[idx]  = exp2f((float)dint[idx] * LOG2_GAMMA);
        }

    floatx4 o[8];
    #pragma unroll
    for (int f = 0; f < 8; ++f) o[f] = (floatx4){0.f, 0.f, 0.f, 0.f};

    // bpermute source-lane byte indices (constant per lane)
    const int s0   = (quad & 1) * 2;
    const int idxA = (s0 * 16 + l16) * 4;
    const int idxB = idxA + 64;
    const bool lo  = (quad < 2);   // target k-subtile nt = quad>>1

    // read-side swizzle keys
    const int xk7 = l16 & 7;                          // K chunks
    const int pvx = (quad ^ ((l16 >> 1) & 3)) << 4;   // V chunk byte

    // ---- prologue ----
    stage(0, kst);
    asm volatile("s_waitcnt vmcnt(0)" ::: "memory");
    __builtin_amdgcn_s_barrier();

    for (int it = 0; it < nsteps; ++it) {
        const int cur = it & 1;
        const int k0  = kst + it * 32;
        if (it + 1 < nsteps) stage(cur ^ 1, k0 + 32);

        const char* kb = (const char*)&Ks[cur][0][0];
        const char* vb = (const char*)&Vt[cur][0][0];

        // ---- swapped QK^T: A = K rows (LDS), B = Q regs; 4 chains
        floatx4 sA0 = (floatx4){0.f, 0.f, 0.f, 0.f};
        floatx4 sA1 = (floatx4){0.f, 0.f, 0.f, 0.f};
        floatx4 sB0 = (floatx4){0.f, 0.f, 0.f, 0.f};
        floatx4 sB1 = (floatx4){0.f, 0.f, 0.f, 0.f};
        __builtin_amdgcn_s_setprio(1);
        #pragma unroll
        for (int dd = 0; dd < 4; ++dd) {
            const int c0 = ((dd * 4 + quad) ^ xk7) << 4;
            const int c1 = (((dd + 4) * 4 + quad) ^ xk7) << 4;
            const short8 k0f = *(const short8*)(kb + l16 * 512 + c0);
            const short8 k1f = *(const short8*)(kb + (16 + l16) * 512 + c0);
            const short8 k0g = *(const short8*)(kb + l16 * 512 + c1);
            const short8 k1g = *(const short8*)(kb + (16 + l16) * 512 + c1);
            sA0 = __builtin_amdgcn_mfma_f32_16x16x32_bf16(k0f, qf[dd], sA0, 0, 0, 0);
            sA1 = __builtin_amdgcn_mfma_f32_16x16x32_bf16(k1f, qf[dd], sA1, 0, 0, 0);
            sB0 = __builtin_amdgcn_mfma_f32_16x16x32_bf16(k0g, qf[dd + 4], sB0, 0, 0, 0);
            sB1 = __builtin_amdgcn_mfma_f32_16x16x32_bf16(k1g, qf[dd + 4], sB1, 0, 0, 0);
        }
        __builtin_amdgcn_s_setprio(0);
        const floatx4 sv0 = sA0 + sB0;   // nt=0: kpos = k0 + quad*4+g
        const floatx4 sv1 = sA1 + sB1;   // nt=1: kpos = k0+16 + quad*4+g

        // ---- decay + pack to bf16 pairs (lane-local)
        unsigned int pk01[2], pk23[2];
        #pragma unroll
        for (int nt = 0; nt < 2; ++nt) {
            const floatx4 sv = nt ? sv1 : sv0;
            float pv[4];
            #pragma unroll
            for (int g = 0; g < 4; ++g) {
                const int idx = nt * 4 + g;
                pv[g] = (dint[idx] >= 0) ? sv[g] * dec[idx] : 0.0f;
            }
            pk01[nt] = ((unsigned int)f2bf(pv[1]) << 16) | (unsigned int)f2bf(pv[0]);
            pk23[nt] = ((unsigned int)f2bf(pv[3]) << 16) | (unsigned int)f2bf(pv[2]);
        }
        #pragma unroll
        for (int i = 0; i < 8; ++i) { dint[i] -= 32; dec[i] *= INV_GAMMA32; }

        // ---- redistribute P to PV A-frag layout: 8 bpermute + 4 selects
        const int a01_0 = __builtin_amdgcn_ds_bpermute(idxA, (int)pk01[0]);
        const int a01_1 = __builtin_amdgcn_ds_bpermute(idxA, (int)pk01[1]);
        const int a23_0 = __builtin_amdgcn_ds_bpermute(idxA, (int)pk23[0]);
        const int a23_1 = __builtin_amdgcn_ds_bpermute(idxA, (int)pk23[1]);
        const int b01_0 = __builtin_amdgcn_ds_bpermute(idxB, (int)pk01[0]);
        const int b01_1 = __builtin_amdgcn_ds_bpermute(idxB, (int)pk01[1]);
        const int b23_0 = __builtin_amdgcn_ds_bpermute(idxB, (int)pk23[0]);
        const int b23_1 = __builtin_amdgcn_ds_bpermute(idxB, (int)pk23[1]);
        union { int u[4]; short8 s8; } af;
        af.u[0] = lo ? a01_0 : a01_1;
        af.u[1] = lo ? a23_0 : a23_1;
        af.u[2] = lo ? b01_0 : b01_1;
        af.u[3] = lo ? b23_0 : b23_1;

        // ---- PV: o[f] += P @ V^T  (A from regs, B from swizzled Vt LDS)
        __builtin_amdgcn_s_setprio(1);
        #pragma unroll
        for (int f = 0; f < 8; ++f) {
            const short8 bfr =
                *(const short8*)(vb + (f * 16 + l16) * 64 + pvx);
            o[f] = __builtin_amdgcn_mfma_f32_16x16x32_bf16(af.s8, bfr, o[f], 0, 0, 0);
        }
        __builtin_amdgcn_s_setprio(0);

        // next tile staged; all reads of cur consumed (compiler lgkm waits
        // precede the MFMAs above)
        asm volatile("s_waitcnt vmcnt(0)" ::: "memory");
        __builtin_amdgcn_s_barrier();
    }

    // direct store: this block owns features z*128 .. z*128+127 exclusively
    #pragma unroll
    for (int f = 0; f < 8; ++f) {
        #pragma unroll
        for (int g = 0; g < 4; ++g) {
            const int qpos = q0 + w16 + quad * 4 + g;
            O[rbase + (size_t)qpos * DH + z * 128 + f * 16 + l16] = o[f][g];
        }
    }
}

// ---------------------------------------------------------------------------
extern "C" void kernel_launch(void* const* d_in, const int* in_sizes, int n_in,
                              void* d_out, int out_size, void* d_ws, size_t ws_size,
                              hipStream_t stream)
{
    const float* X  = (const float*)d_in[0];
    const float* WQ = (const float*)d_in[1];
    const float* WK = (const float*)d_in[2];
    const float* WV = (const float*)d_in[3];
    float* out = (float*)d_out;

    const size_t per = (size_t)BATCH_N * L_SEQ * DH;   // 4,194,304
    unsigned short* Qw  = (unsigned short*)d_ws;
    unsigned short* Kw  = Qw + per;
    unsigned short* Vtw = Kw + per;
    unsigned short* Xbw = Vtw + per;                   // 16,777,216 elems
    unsigned short* Wtw = Xbw + (size_t)16384 * HID;   // 786,432 elems
    float2* tabQ = (float2*)(Wtw + 786432);            // 4 MB (8B-aligned)
    float2* tabK = tabQ + (size_t)128 * L_SEQ;         // 4 MB
    // total workspace: ~68.3 MB

    prep_kernel<<<18624, 256, 0, stream>>>(X, Xbw, tabQ, tabK,
                                           WQ, WK, WV, Wtw);

    gemm_qkv_kernel<<<768, 256, 0, stream>>>(Wtw, Xbw, tabQ, tabK, Qw, Kw, Vtw);

    retention_kernel<<<512, 256, 0, stream>>>(Qw, Kw, Vtw, out);
}